// Round 10
// baseline (230.505 us; speedup 1.0000x reference)
//
#include <hip/hip_runtime.h>

typedef __bf16 bf16;
typedef __bf16 bf16x8 __attribute__((ext_vector_type(8)));
typedef float  f32x4  __attribute__((ext_vector_type(4)));

#define QTOT 1024
#define DD   256

// ============ k_prep: pack W1 weights (blocks 0..95) + qf mean partials & bf16 convert (96..1119) ============
__global__ void k_prep(const float* __restrict__ wr, const float* __restrict__ wt,
                       const float* __restrict__ wm, const float* __restrict__ qf,
                       bf16* __restrict__ pk, float* __restrict__ wsMean2,
                       bf16* __restrict__ qf16, int useQ16) {
  __shared__ float sPart[8][256];
  int blk = blockIdx.x;
  if (blk < 96) {
    int gid = blk * 256 + threadIdx.x;              // 0..24575
    const float* W; int N, nK, idx; bf16* dst;
    if (gid < 4096)      { W = wr; N = 128; nK = 8;  idx = gid;        dst = pk; }
    else if (gid < 8192) { W = wt; N = 128; nK = 8;  idx = gid - 4096; dst = pk + 32768; }
    else                 { W = wm; N = 256; nK = 16; idx = gid - 8192; dst = pk + 65536; }
    int tile = idx >> 6, lane = idx & 63;
    int ni = tile / nK, ki = tile % nK;
    int l15 = lane & 15, quad = lane >> 4;
    int n = ni * 16 + l15;
    int kbase = ki * 32 + quad * 8;
    bf16x8 v;
#pragma unroll
    for (int j = 0; j < 8; ++j) v[j] = (bf16)W[(size_t)(kbase + j) * N + n];
    *(bf16x8*)(dst + (size_t)idx * 8) = v;
  } else {
    int mb = blk - 96;                              // 0..1023 ; 16 blocks per batch
    int b = mb >> 4, chunk = mb & 15;               // 64 rows each
    int tid = threadIdx.x;
    int rg = tid >> 5, c8 = tid & 31;
    float acc[8] = {0.f,0.f,0.f,0.f,0.f,0.f,0.f,0.f};
#pragma unroll
    for (int it = 0; it < 8; ++it) {
      int row = chunk * 64 + it * 8 + rg;
      const float* rp = qf + ((size_t)b * QTOT + row) * DD + c8 * 8;
      f32x4 v0 = *(const f32x4*)rp;
      f32x4 v1 = *(const f32x4*)(rp + 4);
#pragma unroll
      for (int j = 0; j < 4; ++j) { acc[j] += v0[j]; acc[4 + j] += v1[j]; }
      if (useQ16) {
        bf16x8 qv;
#pragma unroll
        for (int j = 0; j < 4; ++j) { qv[j] = (bf16)v0[j]; qv[4 + j] = (bf16)v1[j]; }
        *(bf16x8*)(qf16 + ((size_t)b * QTOT + row) * DD + c8 * 8) = qv;
      }
    }
#pragma unroll
    for (int j = 0; j < 8; ++j) sPart[rg][c8 * 8 + j] = acc[j];
    __syncthreads();
    float s = 0.f;
#pragma unroll
    for (int g = 0; g < 8; ++g) s += sPart[g][tid];
    wsMean2[(size_t)mb * 256 + tid] = s;
  }
}

// ============ k_mid: blocks 0..63 = per-batch tgtpart GEMM, 64..127 = step_scales ============
__global__ void k_mid(const float* __restrict__ tgt_f, const bf16* __restrict__ pk,
                      const float* __restrict__ wsMean2,
                      const float* __restrict__ w1, const float* __restrict__ b1,
                      const float* __restrict__ w2, const float* __restrict__ b2,
                      const float* __restrict__ gs,
                      bf16* __restrict__ tgtp, float* __restrict__ outS) {
  __shared__ __align__(16) bf16 sT[64 * 264];
  __shared__ float sMean[256];
  __shared__ float sPart2[256];
  __shared__ float sHid[128];
  int blk = blockIdx.x, tid = threadIdx.x;
  if (blk < 64) {
    int b = blk;
    const float* srcT = tgt_f + ((size_t)b * 64) * DD;
#pragma unroll
    for (int it = 0; it < 8; ++it) {
      int idx = tid + it * 256;
      int row = idx >> 5, c8 = idx & 31;
      f32x4 t0 = *(const f32x4*)(srcT + (size_t)row * DD + c8 * 8);
      f32x4 t1 = *(const f32x4*)(srcT + (size_t)row * DD + c8 * 8 + 4);
      bf16x8 tv;
#pragma unroll
      for (int j = 0; j < 4; ++j) { tv[j] = (bf16)t0[j]; tv[4 + j] = (bf16)t1[j]; }
      *(bf16x8*)(sT + row * 264 + c8 * 8) = tv;
    }
    __syncthreads();
    const int lane = tid & 63, wv = tid >> 6;
    const int l15 = lane & 15, quad = lane >> 4, koff = quad * 8;
    const bf16x8* pMatch = (const bf16x8*)(pk + 65536);
    f32x4 acc[4][4];
#pragma unroll
    for (int mt = 0; mt < 4; ++mt)
#pragma unroll
      for (int nl = 0; nl < 4; ++nl) acc[mt][nl] = f32x4{0.f, 0.f, 0.f, 0.f};
#pragma unroll
    for (int ks = 0; ks < 8; ++ks) {
      bf16x8 A[4];
#pragma unroll
      for (int mt = 0; mt < 4; ++mt)
        A[mt] = *(const bf16x8*)(sT + (mt * 16 + l15) * 264 + ks * 32 + koff);
#pragma unroll
      for (int nl = 0; nl < 4; ++nl) {
        bf16x8 Bm = pMatch[((size_t)((4 * wv + nl) * 16 + 8 + ks)) * 64 + lane];
#pragma unroll
        for (int mt = 0; mt < 4; ++mt)
          acc[mt][nl] = __builtin_amdgcn_mfma_f32_16x16x32_bf16(A[mt], Bm, acc[mt][nl], 0, 0, 0);
      }
    }
    bf16* dst = tgtp + (size_t)b * 64 * 256;
#pragma unroll
    for (int mt = 0; mt < 4; ++mt)
#pragma unroll
      for (int nl = 0; nl < 4; ++nl) {
        int n = (4 * wv + nl) * 16 + l15;
#pragma unroll
        for (int i = 0; i < 4; ++i) {
          int t = mt * 16 + quad * 4 + i;
          dst[t * 256 + n] = (bf16)acc[mt][nl][i];
        }
      }
  } else {
    int b = blk - 64;
    float s = 0.f;
#pragma unroll
    for (int p = 0; p < 16; ++p) s += wsMean2[(size_t)(b * 16 + p) * 256 + tid];
    sMean[tid] = s * (1.f / 1024.f);
    __syncthreads();
    int hid = tid & 127, half = tid >> 7;
    float ph = 0.f;
#pragma unroll 8
    for (int dd = 0; dd < 128; ++dd) {
      int d = half * 128 + dd;
      ph += sMean[d] * w1[d * 128 + hid];
    }
    sPart2[tid] = ph;
    __syncthreads();
    if (tid < 128) sHid[tid] = fmaxf(sPart2[tid] + sPart2[tid + 128] + b1[tid], 0.f);
    __syncthreads();
    if (tid < 3) {
      float o = b2[tid];
      for (int k = 0; k < 128; ++k) o += sHid[k] * w2[k * 3 + tid];
      float g = fminf(fmaxf(gs[0], 0.f), 1.f);
      outS[b * 3 + tid] = g / (1.f + expf(-o));
    }
  }
}

// ============ k_main: 32 queries/block, ~18.6 KB LDS; (256,6) -> ~6 blocks/CU, no spills ============
__launch_bounds__(256, 6)
__global__ void k_main(const float* __restrict__ pred_boxes, const float* __restrict__ qf,
                       const bf16* __restrict__ qf16, int useQ16,
                       const float* __restrict__ tgt_boxes,
                       const float* __restrict__ rw_b1, const float* __restrict__ rw_w2, const float* __restrict__ rw_b2,
                       const float* __restrict__ tw_b1, const float* __restrict__ tw_w2, const float* __restrict__ tw_b2,
                       const float* __restrict__ mn_b1, const float* __restrict__ mn_w2, const float* __restrict__ mn_b2,
                       const bf16* __restrict__ pk, const bf16* __restrict__ tgtp,
                       f32x4* __restrict__ wsW) {
  __shared__ __align__(16) bf16 sQ[32 * 264];   // 16.9 KB, pad 256->264
  __shared__ float sRedA[4][32];
  __shared__ float sRedB[4][32];
  __shared__ float sRedM[4][32];
  __shared__ int   sNN[32];

  const int tid = threadIdx.x;
  const int b  = blockIdx.x >> 5;
  const int qb = (blockIdx.x & 31) << 5;

  if (useQ16) { // stage pre-converted bf16 qf (pure 16B copies)
    const bf16* srcQ = qf16 + ((size_t)(b * QTOT + qb)) * DD;
#pragma unroll
    for (int it = 0; it < 4; ++it) {
      int idx = tid + it * 256;                // 0..1023
      int row = idx >> 5, c8 = idx & 31;
      *(bf16x8*)(sQ + row * 264 + c8 * 8) = *(const bf16x8*)(srcQ + (size_t)row * DD + c8 * 8);
    }
  } else {      // fallback: fp32 -> bf16 on the fly
    const float* srcQ = qf + ((size_t)(b * QTOT + qb)) * DD;
#pragma unroll
    for (int it = 0; it < 4; ++it) {
      int idx = tid + it * 256;
      int row = idx >> 5, c8 = idx & 31;
      f32x4 q0 = *(const f32x4*)(srcQ + (size_t)row * DD + c8 * 8);
      f32x4 q1 = *(const f32x4*)(srcQ + (size_t)row * DD + c8 * 8 + 4);
      bf16x8 qv;
#pragma unroll
      for (int j = 0; j < 4; ++j) { qv[j] = (bf16)q0[j]; qv[4 + j] = (bf16)q1[j]; }
      *(bf16x8*)(sQ + row * 264 + c8 * 8) = qv;
    }
  }
  { // NN argmin: 8 threads/query, 8 targets each, numpy tie-break
    int q = tid >> 3, ch = tid & 7;
    size_t gq = (size_t)(b * QTOT + qb + q);
    float px = pred_boxes[gq * 4 + 0];
    float py = pred_boxes[gq * 4 + 1];
    const float* tb = tgt_boxes + ((size_t)b * 64 + ch * 8) * 4;
    float best = 3.4e38f; int bi = ch * 8;
    for (int i = 0; i < 8; ++i) {
      f32x4 bx = *(const f32x4*)(tb + (size_t)i * 4);
      float dx = px - bx[0], dy = py - bx[1];
      float d = __fadd_rn(__fmul_rn(dx, dx), __fmul_rn(dy, dy));
      if (d < best) { best = d; bi = ch * 8 + i; }
    }
#pragma unroll
    for (int m = 1; m < 8; m <<= 1) {
      float pv = __shfl_xor(best, m);
      int   pi = __shfl_xor(bi, m);
      if (pv < best || (pv == best && pi < bi)) { best = pv; bi = pi; }
    }
    if (ch == 0) sNN[q] = bi;
  }
  __syncthreads();

  const int lane = tid & 63, wv = tid >> 6;
  const int l15 = lane & 15, quad = lane >> 4;
  const int koff = quad * 8;
  const bf16x8* pRot   = (const bf16x8*)pk;
  const bf16x8* pTrans = (const bf16x8*)(pk + 32768);
  const bf16x8* pMatch = (const bf16x8*)(pk + 65536);

  // ---- pass A-R: rot layer-1, K=256, wave wv -> N-tiles {2wv, 2wv+1} ----
  {
    f32x4 accR[2][2];
#pragma unroll
    for (int mt = 0; mt < 2; ++mt)
#pragma unroll
      for (int nl = 0; nl < 2; ++nl) accR[mt][nl] = f32x4{0.f, 0.f, 0.f, 0.f};
#pragma unroll
    for (int ks = 0; ks < 8; ++ks) {
      bf16x8 A[2];
#pragma unroll
      for (int mt = 0; mt < 2; ++mt)
        A[mt] = *(const bf16x8*)(sQ + (mt * 16 + l15) * 264 + ks * 32 + koff);
#pragma unroll
      for (int nl = 0; nl < 2; ++nl) {
        bf16x8 Br = pRot[((2 * wv + nl) * 8 + ks) * 64 + lane];
#pragma unroll
        for (int mt = 0; mt < 2; ++mt)
          accR[mt][nl] = __builtin_amdgcn_mfma_f32_16x16x32_bf16(A[mt], Br, accR[mt][nl], 0, 0, 0);
      }
    }
    float b1r[2], w2r[2];
#pragma unroll
    for (int nl = 0; nl < 2; ++nl) {
      int n = (2 * wv + nl) * 16 + l15;
      b1r[nl] = rw_b1[n]; w2r[nl] = rw_w2[n];
    }
#pragma unroll
    for (int mt = 0; mt < 2; ++mt)
#pragma unroll
      for (int i = 0; i < 4; ++i) {
        float pr = 0.f;
#pragma unroll
        for (int nl = 0; nl < 2; ++nl) pr += fmaxf(accR[mt][nl][i] + b1r[nl], 0.f) * w2r[nl];
        pr += __shfl_xor(pr, 1); pr += __shfl_xor(pr, 2); pr += __shfl_xor(pr, 4); pr += __shfl_xor(pr, 8);
        if (l15 == 0) sRedA[wv][mt * 16 + quad * 4 + i] = pr;
      }
  }
  // ---- pass A-T: trans layer-1 ----
  {
    f32x4 accT[2][2];
#pragma unroll
    for (int mt = 0; mt < 2; ++mt)
#pragma unroll
      for (int nl = 0; nl < 2; ++nl) accT[mt][nl] = f32x4{0.f, 0.f, 0.f, 0.f};
#pragma unroll
    for (int ks = 0; ks < 8; ++ks) {
      bf16x8 A[2];
#pragma unroll
      for (int mt = 0; mt < 2; ++mt)
        A[mt] = *(const bf16x8*)(sQ + (mt * 16 + l15) * 264 + ks * 32 + koff);
#pragma unroll
      for (int nl = 0; nl < 2; ++nl) {
        bf16x8 Bt = pTrans[((2 * wv + nl) * 8 + ks) * 64 + lane];
#pragma unroll
        for (int mt = 0; mt < 2; ++mt)
          accT[mt][nl] = __builtin_amdgcn_mfma_f32_16x16x32_bf16(A[mt], Bt, accT[mt][nl], 0, 0, 0);
      }
    }
    float b1t[2], w2t[2];
#pragma unroll
    for (int nl = 0; nl < 2; ++nl) {
      int n = (2 * wv + nl) * 16 + l15;
      b1t[nl] = tw_b1[n]; w2t[nl] = tw_w2[n];
    }
#pragma unroll
    for (int mt = 0; mt < 2; ++mt)
#pragma unroll
      for (int i = 0; i < 4; ++i) {
        float pt = 0.f;
#pragma unroll
        for (int nl = 0; nl < 2; ++nl) pt += fmaxf(accT[mt][nl][i] + b1t[nl], 0.f) * w2t[nl];
        pt += __shfl_xor(pt, 1); pt += __shfl_xor(pt, 2); pt += __shfl_xor(pt, 4); pt += __shfl_xor(pt, 8);
        if (l15 == 0) sRedB[wv][mt * 16 + quad * 4 + i] = pt;
      }
  }
  // ---- pass B: match layer-1 qf half (K=256) + precomputed tgtpart, wave -> N-tiles {4wv..4wv+3} ----
  {
    f32x4 accM[2][4];
#pragma unroll
    for (int mt = 0; mt < 2; ++mt)
#pragma unroll
      for (int nl = 0; nl < 4; ++nl) accM[mt][nl] = f32x4{0.f, 0.f, 0.f, 0.f};
#pragma unroll
    for (int ks = 0; ks < 8; ++ks) {
      bf16x8 A[2];
#pragma unroll
      for (int mt = 0; mt < 2; ++mt)
        A[mt] = *(const bf16x8*)(sQ + (mt * 16 + l15) * 264 + ks * 32 + koff);
#pragma unroll
      for (int nl = 0; nl < 4; ++nl) {
        bf16x8 Bm = pMatch[((4 * wv + nl) * 16 + ks) * 64 + lane];
#pragma unroll
        for (int mt = 0; mt < 2; ++mt)
          accM[mt][nl] = __builtin_amdgcn_mfma_f32_16x16x32_bf16(A[mt], Bm, accM[mt][nl], 0, 0, 0);
      }
    }
    float b1m[4], w2m[4];
#pragma unroll
    for (int nl = 0; nl < 4; ++nl) {
      int n = (4 * wv + nl) * 16 + l15;
      b1m[nl] = mn_b1[n]; w2m[nl] = mn_w2[n];
    }
    const bf16* tpb = tgtp + (size_t)b * 64 * 256;
#pragma unroll
    for (int mt = 0; mt < 2; ++mt)
#pragma unroll
      for (int i = 0; i < 4; ++i) {
        int nnq = sNN[mt * 16 + quad * 4 + i];          // broadcast within quad
        const bf16* tprow = tpb + (size_t)nnq * 256;
        float pm = 0.f;
#pragma unroll
        for (int nl = 0; nl < 4; ++nl) {
          float tp = (float)tprow[(4 * wv + nl) * 16 + l15];
          pm += fmaxf(accM[mt][nl][i] + b1m[nl] + tp, 0.f) * w2m[nl];
        }
        pm += __shfl_xor(pm, 1); pm += __shfl_xor(pm, 2); pm += __shfl_xor(pm, 4); pm += __shfl_xor(pm, 8);
        if (l15 == 0) sRedM[wv][mt * 16 + quad * 4 + i] = pm;
      }
  }
  __syncthreads();

  // ---- epilogue: sigmoids, pack {rw,tw,mw,nn} per query ----
  if (tid < 32) {
    int q = tid;
    float vr = sRedA[0][q] + sRedA[1][q] + sRedA[2][q] + sRedA[3][q] + rw_b2[0];
    float vt = sRedB[0][q] + sRedB[1][q] + sRedB[2][q] + sRedB[3][q] + tw_b2[0];
    float vm = sRedM[0][q] + sRedM[1][q] + sRedM[2][q] + sRedM[3][q] + mn_b2[0];
    f32x4 w;
    w[0] = 1.f / (1.f + expf(-vr));
    w[1] = 1.f / (1.f + expf(-vt));
    w[2] = 1.f / (1.f + expf(-vm));
    w[3] = __int_as_float(sNN[q]);
    wsW[(size_t)(b * QTOT + qb + q)] = w;
  }
}

// ============ k_so3: one thread per query, full-parallel transcendental tail ============
__global__ void k_so3(const float* __restrict__ R_pred, const float* __restrict__ t_pred,
                      const float* __restrict__ tgt_R, const float* __restrict__ tgt_t,
                      const f32x4* __restrict__ wsW, const float* __restrict__ scales,
                      float* __restrict__ out) {
  int gq = blockIdx.x * 256 + threadIdx.x;      // 0..65535
  int b = gq >> 10;
  f32x4 w = wsW[gq];
  float rw = w[0], tw = w[1], mw = w[2];
  int nn = __float_as_int(w[3]);
  float R[9], Rm[9], t[3], tm[3];
#pragma unroll
  for (int i = 0; i < 9; ++i) R[i] = R_pred[(size_t)gq * 9 + i];
#pragma unroll
  for (int c = 0; c < 3; ++c) t[c] = t_pred[(size_t)gq * 3 + c];
  size_t gt = (size_t)b * 64 + nn;
#pragma unroll
  for (int i = 0; i < 9; ++i) Rm[i] = tgt_R[gt * 9 + i];
#pragma unroll
  for (int c = 0; c < 3; ++c) tm[c] = tgt_t[gt * 3 + c];

  for (int s = 0; s < 3; ++s) {
    float sc = scales[b * 3 + s];
    float cr = rw * mw * sc, ctr = tw * mw * sc;
    float Ax[9];                                    // R^T @ Rm
#pragma unroll
    for (int i = 0; i < 3; ++i)
#pragma unroll
      for (int j = 0; j < 3; ++j)
        Ax[i * 3 + j] = R[0 + i] * Rm[0 + j] + R[3 + i] * Rm[3 + j] + R[6 + i] * Rm[6 + j];
    float tr = fminf(fmaxf(Ax[0] + Ax[4] + Ax[8], -1.f), 3.f);
    float cthe = fminf(fmaxf((tr - 1.f) * 0.5f, -1.f), 1.f);
    float th = acosf(cthe);
    float vx = 0.5f * (Ax[7] - Ax[5]);
    float vy = 0.5f * (Ax[2] - Ax[6]);
    float vz = 0.5f * (Ax[3] - Ax[1]);
    float f = (th < 1e-5f) ? 1.f : th / fmaxf(sinf(th), 1e-12f);
    float ax = vx * f * cr, ay = vy * f * cr, az = vz * f * cr;
    float th2 = ax * ax + ay * ay + az * az;
    float thn = sqrtf(th2);
    float E[9];
    if (thn < 1e-5f) {                               // I + hat(a) + 0.5 hat(a)^2
      E[0] = 1.f + 0.5f * (ax * ax - th2); E[1] = -az + 0.5f * ax * ay;        E[2] =  ay + 0.5f * ax * az;
      E[3] =  az + 0.5f * ax * ay;         E[4] = 1.f + 0.5f * (ay * ay - th2); E[5] = -ax + 0.5f * ay * az;
      E[6] = -ay + 0.5f * ax * az;         E[7] =  ax + 0.5f * ay * az;         E[8] = 1.f + 0.5f * (az * az - th2);
    } else {                                         // Rodrigues
      float kx = ax / thn, ky = ay / thn, kz = az / thn;
      float st = sinf(thn), co = cosf(thn), c1 = 1.f - co;
      E[0] = co + c1 * kx * kx;      E[1] = c1 * kx * ky - st * kz; E[2] = c1 * kx * kz + st * ky;
      E[3] = c1 * kx * ky + st * kz; E[4] = co + c1 * ky * ky;      E[5] = c1 * ky * kz - st * kx;
      E[6] = c1 * kx * kz - st * ky; E[7] = c1 * ky * kz + st * kx; E[8] = co + c1 * kz * kz;
    }
    float Rn[9];
#pragma unroll
    for (int i = 0; i < 3; ++i)
#pragma unroll
      for (int j = 0; j < 3; ++j)
        Rn[i * 3 + j] = R[i * 3 + 0] * E[j] + R[i * 3 + 1] * E[3 + j] + R[i * 3 + 2] * E[6 + j];
#pragma unroll
    for (int i = 0; i < 9; ++i) R[i] = Rn[i];
#pragma unroll
    for (int c = 0; c < 3; ++c) t[c] += (tm[c] - t[c]) * ctr;
  }
#pragma unroll
  for (int i = 0; i < 9; ++i) out[(size_t)gq * 9 + i] = R[i];
#pragma unroll
  for (int c = 0; c < 3; ++c) out[(size_t)589824 + (size_t)gq * 3 + c] = t[c];
}

extern "C" void kernel_launch(void* const* d_in, const int* in_sizes, int n_in,
                              void* d_out, int out_size, void* d_ws, size_t ws_size,
                              hipStream_t stream) {
  const float* R_pred     = (const float*)d_in[0];
  const float* t_pred     = (const float*)d_in[1];
  const float* pred_boxes = (const float*)d_in[2];
  const float* qf         = (const float*)d_in[3];
  const float* tgt_R      = (const float*)d_in[4];
  const float* tgt_t      = (const float*)d_in[5];
  const float* tgt_boxes  = (const float*)d_in[6];
  const float* tgt_f      = (const float*)d_in[7];
  const float* sp_w1 = (const float*)d_in[8];
  const float* sp_b1 = (const float*)d_in[9];
  const float* sp_w2 = (const float*)d_in[10];
  const float* sp_b2 = (const float*)d_in[11];
  const float* rw_w1 = (const float*)d_in[12];
  const float* rw_b1 = (const float*)d_in[13];
  const float* rw_w2 = (const float*)d_in[14];
  const float* rw_b2 = (const float*)d_in[15];
  const float* tw_w1 = (const float*)d_in[16];
  const float* tw_b1 = (const float*)d_in[17];
  const float* tw_w2 = (const float*)d_in[18];
  const float* tw_b2 = (const float*)d_in[19];
  const float* mn_w1 = (const float*)d_in[20];
  const float* mn_b1 = (const float*)d_in[21];
  const float* mn_w2 = (const float*)d_in[22];
  const float* mn_b2 = (const float*)d_in[23];
  const float* gs    = (const float*)d_in[24];

  char* ws = (char*)d_ws;
  float* wsScales = (float*)ws;                               // 1 KB
  float* wsMean2  = (float*)(ws + 1024);                      // 1024*256*4 = 1 MB
  bf16*  pk       = (bf16*)(ws + 1024 + 1048576);             // 384 KB
  bf16*  tgtp     = (bf16*)(ws + 1024 + 1048576 + 393216);    // 2 MB
  f32x4* wsW      = (f32x4*)(ws + 1024 + 1048576 + 393216 + 2097152);            // 1 MB
  bf16*  qf16     = (bf16*)(ws + 1024 + 1048576 + 393216 + 2097152 + 1048576);   // 32 MB optional
  size_t need16   = 1024 + 1048576 + 393216 + 2097152 + 1048576 + (size_t)QTOT * 64 * DD * 2;
  int useQ16      = (ws_size >= need16) ? 1 : 0;
  float* out      = (float*)d_out;

  k_prep<<<1120, 256, 0, stream>>>(rw_w1, tw_w1, mn_w1, qf, pk, wsMean2, qf16, useQ16);
  k_mid<<<128, 256, 0, stream>>>(tgt_f, pk, wsMean2, sp_w1, sp_b1, sp_w2, sp_b2, gs, tgtp, wsScales);
  k_main<<<2048, 256, 0, stream>>>(pred_boxes, qf, qf16, useQ16, tgt_boxes,
                                   rw_b1, rw_w2, rw_b2, tw_b1, tw_w2, tw_b2, mn_b1, mn_w2, mn_b2,
                                   pk, tgtp, wsW);
  k_so3<<<256, 256, 0, stream>>>(R_pred, t_pred, tgt_R, tgt_t, wsW, wsScales, out);
}

// Round 11
// 204.178 us; speedup vs baseline: 1.1289x; 1.1289x over previous
//
#include <hip/hip_runtime.h>

typedef __bf16 bf16;
typedef __bf16 bf16x8 __attribute__((ext_vector_type(8)));
typedef float  f32x4  __attribute__((ext_vector_type(4)));

#define QTOT 1024
#define DD   256

// ============ k_prep: pack W1 weights (blocks 0..95) + qf mean partials (96..1119) ============
__global__ void k_prep(const float* __restrict__ wr, const float* __restrict__ wt,
                       const float* __restrict__ wm, const float* __restrict__ qf,
                       bf16* __restrict__ pk, float* __restrict__ wsMean2) {
  __shared__ float sPart[8][256];
  int blk = blockIdx.x;
  if (blk < 96) {
    int gid = blk * 256 + threadIdx.x;              // 0..24575
    const float* W; int N, nK, idx; bf16* dst;
    if (gid < 4096)      { W = wr; N = 128; nK = 8;  idx = gid;        dst = pk; }
    else if (gid < 8192) { W = wt; N = 128; nK = 8;  idx = gid - 4096; dst = pk + 32768; }
    else                 { W = wm; N = 256; nK = 16; idx = gid - 8192; dst = pk + 65536; }
    int tile = idx >> 6, lane = idx & 63;
    int ni = tile / nK, ki = tile % nK;
    int l15 = lane & 15, quad = lane >> 4;
    int n = ni * 16 + l15;
    int kbase = ki * 32 + quad * 8;
    bf16x8 v;
#pragma unroll
    for (int j = 0; j < 8; ++j) v[j] = (bf16)W[(size_t)(kbase + j) * N + n];
    *(bf16x8*)(dst + (size_t)idx * 8) = v;
  } else {
    int mb = blk - 96;                              // 0..1023 ; 16 blocks per batch
    int b = mb >> 4, chunk = mb & 15;               // 64 rows each
    int tid = threadIdx.x;
    int rg = tid >> 5, c8 = tid & 31;
    float acc[8] = {0.f,0.f,0.f,0.f,0.f,0.f,0.f,0.f};
#pragma unroll
    for (int it = 0; it < 8; ++it) {
      int row = chunk * 64 + it * 8 + rg;
      const float* rp = qf + ((size_t)b * QTOT + row) * DD + c8 * 8;
      f32x4 v0 = *(const f32x4*)rp;
      f32x4 v1 = *(const f32x4*)(rp + 4);
#pragma unroll
      for (int j = 0; j < 4; ++j) { acc[j] += v0[j]; acc[4 + j] += v1[j]; }
    }
#pragma unroll
    for (int j = 0; j < 8; ++j) sPart[rg][c8 * 8 + j] = acc[j];
    __syncthreads();
    float s = 0.f;
#pragma unroll
    for (int g = 0; g < 8; ++g) s += sPart[g][tid];
    wsMean2[(size_t)mb * 256 + tid] = s;
  }
}

// ============ k_mid: blocks 0..63 = per-batch tgtpart GEMM, 64..127 = step_scales ============
__global__ void k_mid(const float* __restrict__ tgt_f, const bf16* __restrict__ pk,
                      const float* __restrict__ wsMean2,
                      const float* __restrict__ w1, const float* __restrict__ b1,
                      const float* __restrict__ w2, const float* __restrict__ b2,
                      const float* __restrict__ gs,
                      bf16* __restrict__ tgtp, float* __restrict__ outS) {
  __shared__ __align__(16) bf16 sT[64 * 264];
  __shared__ float sMean[256];
  __shared__ float sPart2[256];
  __shared__ float sHid[128];
  int blk = blockIdx.x, tid = threadIdx.x;
  if (blk < 64) {
    int b = blk;
    const float* srcT = tgt_f + ((size_t)b * 64) * DD;
#pragma unroll
    for (int it = 0; it < 8; ++it) {
      int idx = tid + it * 256;
      int row = idx >> 5, c8 = idx & 31;
      f32x4 t0 = *(const f32x4*)(srcT + (size_t)row * DD + c8 * 8);
      f32x4 t1 = *(const f32x4*)(srcT + (size_t)row * DD + c8 * 8 + 4);
      bf16x8 tv;
#pragma unroll
      for (int j = 0; j < 4; ++j) { tv[j] = (bf16)t0[j]; tv[4 + j] = (bf16)t1[j]; }
      *(bf16x8*)(sT + row * 264 + c8 * 8) = tv;
    }
    __syncthreads();
    const int lane = tid & 63, wv = tid >> 6;
    const int l15 = lane & 15, quad = lane >> 4, koff = quad * 8;
    const bf16x8* pMatch = (const bf16x8*)(pk + 65536);
    f32x4 acc[4][4];
#pragma unroll
    for (int mt = 0; mt < 4; ++mt)
#pragma unroll
      for (int nl = 0; nl < 4; ++nl) acc[mt][nl] = f32x4{0.f, 0.f, 0.f, 0.f};
#pragma unroll
    for (int ks = 0; ks < 8; ++ks) {
      bf16x8 A[4];
#pragma unroll
      for (int mt = 0; mt < 4; ++mt)
        A[mt] = *(const bf16x8*)(sT + (mt * 16 + l15) * 264 + ks * 32 + koff);
#pragma unroll
      for (int nl = 0; nl < 4; ++nl) {
        bf16x8 Bm = pMatch[((size_t)((4 * wv + nl) * 16 + 8 + ks)) * 64 + lane];
#pragma unroll
        for (int mt = 0; mt < 4; ++mt)
          acc[mt][nl] = __builtin_amdgcn_mfma_f32_16x16x32_bf16(A[mt], Bm, acc[mt][nl], 0, 0, 0);
      }
    }
    bf16* dst = tgtp + (size_t)b * 64 * 256;
#pragma unroll
    for (int mt = 0; mt < 4; ++mt)
#pragma unroll
      for (int nl = 0; nl < 4; ++nl) {
        int n = (4 * wv + nl) * 16 + l15;
#pragma unroll
        for (int i = 0; i < 4; ++i) {
          int t = mt * 16 + quad * 4 + i;
          dst[t * 256 + n] = (bf16)acc[mt][nl][i];
        }
      }
  } else {
    int b = blk - 64;
    float s = 0.f;
#pragma unroll
    for (int p = 0; p < 16; ++p) s += wsMean2[(size_t)(b * 16 + p) * 256 + tid];
    sMean[tid] = s * (1.f / 1024.f);
    __syncthreads();
    int hid = tid & 127, half = tid >> 7;
    float ph = 0.f;
#pragma unroll 8
    for (int dd = 0; dd < 128; ++dd) {
      int d = half * 128 + dd;
      ph += sMean[d] * w1[d * 128 + hid];
    }
    sPart2[tid] = ph;
    __syncthreads();
    if (tid < 128) sHid[tid] = fmaxf(sPart2[tid] + sPart2[tid + 128] + b1[tid], 0.f);
    __syncthreads();
    if (tid < 3) {
      float o = b2[tid];
      for (int k = 0; k < 128; ++k) o += sHid[k] * w2[k * 3 + tid];
      float g = fminf(fmaxf(gs[0], 0.f), 1.f);
      outS[b * 3 + tid] = g / (1.f + expf(-o));
    }
  }
}

// ============ k_main: r4's best-measured kernel — 64q/block, fp32 staging, fused SO3 tail ============
__launch_bounds__(256, 4)
__global__ void k_main(const float* __restrict__ R_pred, const float* __restrict__ t_pred,
                       const float* __restrict__ pred_boxes, const float* __restrict__ qf,
                       const float* __restrict__ tgt_R, const float* __restrict__ tgt_t,
                       const float* __restrict__ tgt_boxes,
                       const float* __restrict__ rw_b1, const float* __restrict__ rw_w2, const float* __restrict__ rw_b2,
                       const float* __restrict__ tw_b1, const float* __restrict__ tw_w2, const float* __restrict__ tw_b2,
                       const float* __restrict__ mn_b1, const float* __restrict__ mn_w2, const float* __restrict__ mn_b2,
                       const bf16* __restrict__ pk, const bf16* __restrict__ tgtp,
                       const float* __restrict__ scales, float* __restrict__ out) {
  __shared__ __align__(16) bf16 sQ[64 * 264];   // pad 256->264 (4-bank row shift)
  __shared__ float sRedA[4][64];
  __shared__ float sRedB[4][64];
  __shared__ float sRedM[4][64];
  __shared__ int   sNN[64];

  const int tid = threadIdx.x;
  const int b  = blockIdx.x >> 4;
  const int qb = (blockIdx.x & 15) << 6;

  { // stage qf tile: fp32 global -> bf16 LDS
    const float* srcQ = qf + ((size_t)(b * QTOT + qb)) * DD;
#pragma unroll
    for (int it = 0; it < 8; ++it) {
      int idx = tid + it * 256;                // 0..2047
      int row = idx >> 5, c8 = idx & 31;
      f32x4 q0 = *(const f32x4*)(srcQ + (size_t)row * DD + c8 * 8);
      f32x4 q1 = *(const f32x4*)(srcQ + (size_t)row * DD + c8 * 8 + 4);
      bf16x8 qv;
#pragma unroll
      for (int j = 0; j < 4; ++j) { qv[j] = (bf16)q0[j]; qv[4 + j] = (bf16)q1[j]; }
      *(bf16x8*)(sQ + row * 264 + c8 * 8) = qv;
    }
  }
  { // NN argmin: 4 threads/query, 16 targets each, numpy tie-break
    int q = tid >> 2, ch = tid & 3;
    size_t gq = (size_t)(b * QTOT + qb + q);
    float px = pred_boxes[gq * 4 + 0];
    float py = pred_boxes[gq * 4 + 1];
    const float* tb = tgt_boxes + ((size_t)b * 64 + ch * 16) * 4;
    float best = 3.4e38f; int bi = ch * 16;
    for (int i = 0; i < 16; ++i) {
      f32x4 bx = *(const f32x4*)(tb + (size_t)i * 4);
      float dx = px - bx[0], dy = py - bx[1];
      float d = __fadd_rn(__fmul_rn(dx, dx), __fmul_rn(dy, dy));
      if (d < best) { best = d; bi = ch * 16 + i; }
    }
#pragma unroll
    for (int m = 1; m < 4; m <<= 1) {
      float pv = __shfl_xor(best, m);
      int   pi = __shfl_xor(bi, m);
      if (pv < best || (pv == best && pi < bi)) { best = pv; bi = pi; }
    }
    if ((tid & 3) == 0) sNN[q] = bi;
  }
  __syncthreads();

  const int lane = tid & 63, wv = tid >> 6;
  const int l15 = lane & 15, quad = lane >> 4;
  const int koff = quad * 8;
  const bf16x8* pRot   = (const bf16x8*)pk;
  const bf16x8* pTrans = (const bf16x8*)(pk + 32768);
  const bf16x8* pMatch = (const bf16x8*)(pk + 65536);

  // ---- pass A-R: rot layer-1, K=256 ----
  {
    f32x4 accR[4][2];
#pragma unroll
    for (int mt = 0; mt < 4; ++mt)
#pragma unroll
      for (int nl = 0; nl < 2; ++nl) accR[mt][nl] = f32x4{0.f, 0.f, 0.f, 0.f};
#pragma unroll
    for (int ks = 0; ks < 8; ++ks) {
      bf16x8 A[4];
#pragma unroll
      for (int mt = 0; mt < 4; ++mt)
        A[mt] = *(const bf16x8*)(sQ + (mt * 16 + l15) * 264 + ks * 32 + koff);
#pragma unroll
      for (int nl = 0; nl < 2; ++nl) {
        bf16x8 Br = pRot[((2 * wv + nl) * 8 + ks) * 64 + lane];
#pragma unroll
        for (int mt = 0; mt < 4; ++mt)
          accR[mt][nl] = __builtin_amdgcn_mfma_f32_16x16x32_bf16(A[mt], Br, accR[mt][nl], 0, 0, 0);
      }
    }
    float b1r[2], w2r[2];
#pragma unroll
    for (int nl = 0; nl < 2; ++nl) {
      int n = (2 * wv + nl) * 16 + l15;
      b1r[nl] = rw_b1[n]; w2r[nl] = rw_w2[n];
    }
#pragma unroll
    for (int mt = 0; mt < 4; ++mt)
#pragma unroll
      for (int i = 0; i < 4; ++i) {
        float pr = 0.f;
#pragma unroll
        for (int nl = 0; nl < 2; ++nl) pr += fmaxf(accR[mt][nl][i] + b1r[nl], 0.f) * w2r[nl];
        pr += __shfl_xor(pr, 1); pr += __shfl_xor(pr, 2); pr += __shfl_xor(pr, 4); pr += __shfl_xor(pr, 8);
        if (l15 == 0) sRedA[wv][mt * 16 + quad * 4 + i] = pr;
      }
  }
  // ---- pass A-T: trans layer-1 ----
  {
    f32x4 accT[4][2];
#pragma unroll
    for (int mt = 0; mt < 4; ++mt)
#pragma unroll
      for (int nl = 0; nl < 2; ++nl) accT[mt][nl] = f32x4{0.f, 0.f, 0.f, 0.f};
#pragma unroll
    for (int ks = 0; ks < 8; ++ks) {
      bf16x8 A[4];
#pragma unroll
      for (int mt = 0; mt < 4; ++mt)
        A[mt] = *(const bf16x8*)(sQ + (mt * 16 + l15) * 264 + ks * 32 + koff);
#pragma unroll
      for (int nl = 0; nl < 2; ++nl) {
        bf16x8 Bt = pTrans[((2 * wv + nl) * 8 + ks) * 64 + lane];
#pragma unroll
        for (int mt = 0; mt < 4; ++mt)
          accT[mt][nl] = __builtin_amdgcn_mfma_f32_16x16x32_bf16(A[mt], Bt, accT[mt][nl], 0, 0, 0);
      }
    }
    float b1t[2], w2t[2];
#pragma unroll
    for (int nl = 0; nl < 2; ++nl) {
      int n = (2 * wv + nl) * 16 + l15;
      b1t[nl] = tw_b1[n]; w2t[nl] = tw_w2[n];
    }
#pragma unroll
    for (int mt = 0; mt < 4; ++mt)
#pragma unroll
      for (int i = 0; i < 4; ++i) {
        float pt = 0.f;
#pragma unroll
        for (int nl = 0; nl < 2; ++nl) pt += fmaxf(accT[mt][nl][i] + b1t[nl], 0.f) * w2t[nl];
        pt += __shfl_xor(pt, 1); pt += __shfl_xor(pt, 2); pt += __shfl_xor(pt, 4); pt += __shfl_xor(pt, 8);
        if (l15 == 0) sRedB[wv][mt * 16 + quad * 4 + i] = pt;
      }
  }
  // ---- pass B: match layer-1 qf half (K=256) + precomputed tgtpart gather ----
  {
    f32x4 accM[4][4];
#pragma unroll
    for (int mt = 0; mt < 4; ++mt)
#pragma unroll
      for (int nl = 0; nl < 4; ++nl) accM[mt][nl] = f32x4{0.f, 0.f, 0.f, 0.f};
#pragma unroll
    for (int ks = 0; ks < 8; ++ks) {
      bf16x8 A[4];
#pragma unroll
      for (int mt = 0; mt < 4; ++mt)
        A[mt] = *(const bf16x8*)(sQ + (mt * 16 + l15) * 264 + ks * 32 + koff);
#pragma unroll
      for (int nl = 0; nl < 4; ++nl) {
        bf16x8 Bm = pMatch[((4 * wv + nl) * 16 + ks) * 64 + lane];
#pragma unroll
        for (int mt = 0; mt < 4; ++mt)
          accM[mt][nl] = __builtin_amdgcn_mfma_f32_16x16x32_bf16(A[mt], Bm, accM[mt][nl], 0, 0, 0);
      }
    }
    float b1m[4], w2m[4];
#pragma unroll
    for (int nl = 0; nl < 4; ++nl) {
      int n = (4 * wv + nl) * 16 + l15;
      b1m[nl] = mn_b1[n]; w2m[nl] = mn_w2[n];
    }
    const bf16* tpb = tgtp + (size_t)b * 64 * 256;
#pragma unroll
    for (int mt = 0; mt < 4; ++mt)
#pragma unroll
      for (int i = 0; i < 4; ++i) {
        int nnq = sNN[mt * 16 + quad * 4 + i];          // broadcast within quad
        const bf16* tprow = tpb + (size_t)nnq * 256;
        float pm = 0.f;
#pragma unroll
        for (int nl = 0; nl < 4; ++nl) {
          float tp = (float)tprow[(4 * wv + nl) * 16 + l15];
          pm += fmaxf(accM[mt][nl][i] + b1m[nl] + tp, 0.f) * w2m[nl];
        }
        pm += __shfl_xor(pm, 1); pm += __shfl_xor(pm, 2); pm += __shfl_xor(pm, 4); pm += __shfl_xor(pm, 8);
        if (l15 == 0) sRedM[wv][mt * 16 + quad * 4 + i] = pm;
      }
  }
  __syncthreads();

  // ---- SO3 refinement + output: one thread per query (fused tail — measured free in r4) ----
  if (tid < 64) {
    int q = tid;
    float vr = sRedA[0][q] + sRedA[1][q] + sRedA[2][q] + sRedA[3][q] + rw_b2[0];
    float vt = sRedB[0][q] + sRedB[1][q] + sRedB[2][q] + sRedB[3][q] + tw_b2[0];
    float vm = sRedM[0][q] + sRedM[1][q] + sRedM[2][q] + sRedM[3][q] + mn_b2[0];
    float rw = 1.f / (1.f + expf(-vr));
    float tw = 1.f / (1.f + expf(-vt));
    float mw = 1.f / (1.f + expf(-vm));
    size_t gq = (size_t)(b * QTOT + qb + q);
    float R[9], Rm[9], t[3], tm[3];
#pragma unroll
    for (int i = 0; i < 9; ++i) R[i] = R_pred[gq * 9 + i];
#pragma unroll
    for (int c = 0; c < 3; ++c) t[c] = t_pred[gq * 3 + c];
    size_t gt = (size_t)b * 64 + sNN[q];
#pragma unroll
    for (int i = 0; i < 9; ++i) Rm[i] = tgt_R[gt * 9 + i];
#pragma unroll
    for (int c = 0; c < 3; ++c) tm[c] = tgt_t[gt * 3 + c];

    for (int s = 0; s < 3; ++s) {
      float sc = scales[b * 3 + s];
      float cr = rw * mw * sc, ctr = tw * mw * sc;
      float Ax[9];                                    // R^T @ Rm
#pragma unroll
      for (int i = 0; i < 3; ++i)
#pragma unroll
        for (int j = 0; j < 3; ++j)
          Ax[i * 3 + j] = R[0 + i] * Rm[0 + j] + R[3 + i] * Rm[3 + j] + R[6 + i] * Rm[6 + j];
      float tr = fminf(fmaxf(Ax[0] + Ax[4] + Ax[8], -1.f), 3.f);
      float cthe = fminf(fmaxf((tr - 1.f) * 0.5f, -1.f), 1.f);
      float th = acosf(cthe);
      float vx = 0.5f * (Ax[7] - Ax[5]);
      float vy = 0.5f * (Ax[2] - Ax[6]);
      float vz = 0.5f * (Ax[3] - Ax[1]);
      float f = (th < 1e-5f) ? 1.f : th / fmaxf(sinf(th), 1e-12f);
      float ax = vx * f * cr, ay = vy * f * cr, az = vz * f * cr;
      float th2 = ax * ax + ay * ay + az * az;
      float thn = sqrtf(th2);
      float E[9];
      if (thn < 1e-5f) {                               // I + hat(a) + 0.5 hat(a)^2
        E[0] = 1.f + 0.5f * (ax * ax - th2); E[1] = -az + 0.5f * ax * ay;        E[2] =  ay + 0.5f * ax * az;
        E[3] =  az + 0.5f * ax * ay;         E[4] = 1.f + 0.5f * (ay * ay - th2); E[5] = -ax + 0.5f * ay * az;
        E[6] = -ay + 0.5f * ax * az;         E[7] =  ax + 0.5f * ay * az;         E[8] = 1.f + 0.5f * (az * az - th2);
      } else {                                         // Rodrigues
        float kx = ax / thn, ky = ay / thn, kz = az / thn;
        float st = sinf(thn), co = cosf(thn), c1 = 1.f - co;
        E[0] = co + c1 * kx * kx;      E[1] = c1 * kx * ky - st * kz; E[2] = c1 * kx * kz + st * ky;
        E[3] = c1 * kx * ky + st * kz; E[4] = co + c1 * ky * ky;      E[5] = c1 * ky * kz - st * kx;
        E[6] = c1 * kx * kz - st * ky; E[7] = c1 * ky * kz + st * kx; E[8] = co + c1 * kz * kz;
      }
      float Rn[9];
#pragma unroll
      for (int i = 0; i < 3; ++i)
#pragma unroll
        for (int j = 0; j < 3; ++j)
          Rn[i * 3 + j] = R[i * 3 + 0] * E[j] + R[i * 3 + 1] * E[3 + j] + R[i * 3 + 2] * E[6 + j];
#pragma unroll
      for (int i = 0; i < 9; ++i) R[i] = Rn[i];
#pragma unroll
      for (int c = 0; c < 3; ++c) t[c] += (tm[c] - t[c]) * ctr;
    }
#pragma unroll
    for (int i = 0; i < 9; ++i) out[gq * 9 + i] = R[i];
#pragma unroll
    for (int c = 0; c < 3; ++c) out[(size_t)589824 + gq * 3 + c] = t[c];
  }
}

extern "C" void kernel_launch(void* const* d_in, const int* in_sizes, int n_in,
                              void* d_out, int out_size, void* d_ws, size_t ws_size,
                              hipStream_t stream) {
  const float* R_pred     = (const float*)d_in[0];
  const float* t_pred     = (const float*)d_in[1];
  const float* pred_boxes = (const float*)d_in[2];
  const float* qf         = (const float*)d_in[3];
  const float* tgt_R      = (const float*)d_in[4];
  const float* tgt_t      = (const float*)d_in[5];
  const float* tgt_boxes  = (const float*)d_in[6];
  const float* tgt_f      = (const float*)d_in[7];
  const float* sp_w1 = (const float*)d_in[8];
  const float* sp_b1 = (const float*)d_in[9];
  const float* sp_w2 = (const float*)d_in[10];
  const float* sp_b2 = (const float*)d_in[11];
  const float* rw_w1 = (const float*)d_in[12];
  const float* rw_b1 = (const float*)d_in[13];
  const float* rw_w2 = (const float*)d_in[14];
  const float* rw_b2 = (const float*)d_in[15];
  const float* tw_w1 = (const float*)d_in[16];
  const float* tw_b1 = (const float*)d_in[17];
  const float* tw_w2 = (const float*)d_in[18];
  const float* tw_b2 = (const float*)d_in[19];
  const float* mn_w1 = (const float*)d_in[20];
  const float* mn_b1 = (const float*)d_in[21];
  const float* mn_w2 = (const float*)d_in[22];
  const float* mn_b2 = (const float*)d_in[23];
  const float* gs    = (const float*)d_in[24];

  char* ws = (char*)d_ws;
  float* wsScales = (float*)ws;                               // 1 KB
  float* wsMean2  = (float*)(ws + 1024);                      // 1024*256*4 = 1 MB
  bf16*  pk       = (bf16*)(ws + 1024 + 1048576);             // 384 KB
  bf16*  tgtp     = (bf16*)(ws + 1024 + 1048576 + 393216);    // 2 MB
  float* out      = (float*)d_out;

  k_prep<<<1120, 256, 0, stream>>>(rw_w1, tw_w1, mn_w1, qf, pk, wsMean2);
  k_mid<<<128, 256, 0, stream>>>(tgt_f, pk, wsMean2, sp_w1, sp_b1, sp_w2, sp_b2, gs, tgtp, wsScales);
  k_main<<<1024, 256, 0, stream>>>(R_pred, t_pred, pred_boxes, qf, tgt_R, tgt_t, tgt_boxes,
                                   rw_b1, rw_w2, rw_b2, tw_b1, tw_w2, tw_b2, mn_b1, mn_w2, mn_b2,
                                   pk, tgtp, wsScales, out);
}